// Round 1
// baseline (235.420 us; speedup 1.0000x reference)
//
#include <hip/hip_runtime.h>

// ---------------------------------------------------------------------------
// MultiheadSelfAttention: x[2,2048,1024] f32, w_qkv[3072,1024] f32,
// w_out[1024,1024] f32 -> out[2,2048,1024] f32.
// Pipeline: cast->bf16, qkv = x @ w_qkv^T (MFMA), causal flash attention,
// out = ctx @ w_out^T (MFMA, fp32 out). fp32 accumulation everywhere.
// ---------------------------------------------------------------------------

typedef short short8 __attribute__((ext_vector_type(8)));
typedef float f32x4 __attribute__((ext_vector_type(4)));
typedef unsigned short u16;

#define T_SEQ 2048
#define N_B 2
#define N_H 16
#define HD 64
#define DM 1024
#define TRIPLE 3072

// round-to-nearest-even f32 -> bf16 bits
__device__ __forceinline__ u16 f2bf(float f) {
  union { float f; unsigned u; } v;
  v.f = f;
  unsigned r = v.u + 0x7fffu + ((v.u >> 16) & 1u);
  return (u16)(r >> 16);
}

typedef const __attribute__((address_space(1))) void gvoid;
typedef __attribute__((address_space(3))) void lvoid;

// async global->LDS, 16B per lane; lds dest = wave-uniform base + lane*16
__device__ __forceinline__ void g2l16(const void* g, void* l) {
  __builtin_amdgcn_global_load_lds((gvoid*)g, (lvoid*)l, 16, 0, 0);
}

__device__ __forceinline__ void storeC(float* p, float v) { *p = v; }
__device__ __forceinline__ void storeC(u16* p, float v) { *p = f2bf(v); }

// ---------------------------------------------------------------------------
__global__ __launch_bounds__(256) void cast_bf16(const float4* __restrict__ in,
                                                 ushort4* __restrict__ out, int n4) {
  int i = blockIdx.x * 256 + threadIdx.x;
  if (i < n4) {
    float4 v = in[i];
    ushort4 o;
    o.x = f2bf(v.x); o.y = f2bf(v.y); o.z = f2bf(v.z); o.w = f2bf(v.w);
    out[i] = o;
  }
}

// ---------------------------------------------------------------------------
// C[M][N] = A[M][K] * W[N][K]^T   (bf16 in, fp32 acc, OutT out)
// 128x128 tile, BK=64, 4 waves, global_load_lds w/ pre-swizzled source,
// XOR-swizzled ds_read_b128 (conflict-free).
// ---------------------------------------------------------------------------
template <typename OutT>
__global__ __launch_bounds__(256) void gemm_bt(const u16* __restrict__ A,
                                               const u16* __restrict__ W,
                                               OutT* __restrict__ C,
                                               int M, int N, int K) {
  __shared__ char As[128 * 64 * 2];
  __shared__ char Bs[128 * 64 * 2];
  const int tid = threadIdx.x;
  const int lane = tid & 63, w = tid >> 6;
  const int l15 = lane & 15, l4 = lane >> 4;
  const int m0 = blockIdx.y * 128, n0 = blockIdx.x * 128;
  const int wr = (w >> 1) * 64, wc = (w & 1) * 64;

  const f32x4 zero = {0.f, 0.f, 0.f, 0.f};
  f32x4 acc[4][4];
#pragma unroll
  for (int m = 0; m < 4; ++m)
#pragma unroll
    for (int n = 0; n < 4; ++n) acc[m][n] = zero;

  for (int k0 = 0; k0 < K; k0 += 64) {
    // stage A,B tiles: 1024 chunks of 16B each; LDS linear, source pre-swizzled
#pragma unroll
    for (int i = 0; i < 4; ++i) {
      const int cb = (i * 4 + w) * 64;  // wave-uniform chunk base
      const int c = cb + lane;
      const int row = c >> 3;
      const int ks = ((c & 7) ^ (row & 7)) * 8;  // swizzled k-chunk
      g2l16(A + (size_t)(m0 + row) * K + k0 + ks, As + (size_t)cb * 16);
      g2l16(W + (size_t)(n0 + row) * K + k0 + ks, Bs + (size_t)cb * 16);
    }
    __syncthreads();  // drains vmcnt(0) -> tiles visible

#pragma unroll
    for (int kk = 0; kk < 2; ++kk) {
      short8 a[4], b[4];
#pragma unroll
      for (int m = 0; m < 4; ++m) {
        int row = wr + m * 16 + l15;
        int slot = (kk * 4 + l4) ^ (row & 7);
        a[m] = *(const short8*)(As + row * 128 + slot * 16);
      }
#pragma unroll
      for (int n = 0; n < 4; ++n) {
        int row = wc + n * 16 + l15;
        int slot = (kk * 4 + l4) ^ (row & 7);
        b[n] = *(const short8*)(Bs + row * 128 + slot * 16);
      }
#pragma unroll
      for (int m = 0; m < 4; ++m)
#pragma unroll
        for (int n = 0; n < 4; ++n)
          acc[m][n] = __builtin_amdgcn_mfma_f32_16x16x32_bf16(a[m], b[n], acc[m][n], 0, 0, 0);
    }
    __syncthreads();  // protect tiles before next overwrite
  }

  // epilogue: D row = l4*4 + r, col = l15 (per 16x16 fragment)
#pragma unroll
  for (int m = 0; m < 4; ++m)
#pragma unroll
    for (int n = 0; n < 4; ++n)
#pragma unroll
      for (int r = 0; r < 4; ++r) {
        int row = m0 + wr + m * 16 + l4 * 4 + r;
        int col = n0 + wc + n * 16 + l15;
        storeC(C + (size_t)row * N + col, acc[m][n][r]);
      }
}

// ---------------------------------------------------------------------------
// Causal flash attention. qkv: [B*T][3072] bf16 (q|k|v each [h*64+d]).
// Block: 4 waves = 64 q-rows for one (b,h). K-tiles of 64 keys.
// ctx out: [B*T][1024] bf16 (head-major columns).
// ---------------------------------------------------------------------------
__global__ __launch_bounds__(256) void attn_fwd(const u16* __restrict__ qkv,
                                                u16* __restrict__ ctx) {
  __shared__ char Ks[64 * 64 * 2];      // swizzled K tile [key][d]
  __shared__ u16 Vt[64][72];            // V^T tile [d][key], padded
  __shared__ u16 Pl[4][16][72];         // per-wave P [qrow][key], padded
  const int tid = threadIdx.x;
  const int lane = tid & 63, w = tid >> 6;
  const int l15 = lane & 15, l4 = lane >> 4;
  const int qt = blockIdx.x, h = blockIdx.y, b = blockIdx.z;
  const int q0 = qt * 64;

  // Q fragments: A[m=qrow][k=d], lane holds Q[l15][l4*8+e (+32*kk)]
  short8 qa[2];
  {
    const u16* qp = qkv + (size_t)(b * T_SEQ + q0 + w * 16 + l15) * TRIPLE + h * HD;
    qa[0] = *(const short8*)(qp + l4 * 8);
    qa[1] = *(const short8*)(qp + 32 + l4 * 8);
  }

  const f32x4 zero = {0.f, 0.f, 0.f, 0.f};
  f32x4 o[4];
  float mr[4], lr[4];
#pragma unroll
  for (int nt = 0; nt < 4; ++nt) o[nt] = zero;
#pragma unroll
  for (int r = 0; r < 4; ++r) { mr[r] = -INFINITY; lr[r] = 0.f; }

  for (int kt = 0; kt <= qt; ++kt) {
    const int k0 = kt * 64;
    __syncthreads();  // prior tile's reads complete before overwrite

    // stage K tile (512 x 16B chunks), swizzled source, linear LDS
#pragma unroll
    for (int i = 0; i < 2; ++i) {
      const int cb = (i * 4 + w) * 64;
      const int c = cb + lane;
      const int row = c >> 3;
      const int ks = ((c & 7) ^ (row & 7)) * 8;
      g2l16(qkv + (size_t)(b * T_SEQ + k0 + row) * TRIPLE + DM + h * HD + ks,
            Ks + (size_t)cb * 16);
    }
    // stage V transposed: read 8 contiguous d, scatter to Vt[d][key]
#pragma unroll
    for (int i = 0; i < 2; ++i) {
      const int c = tid + i * 256;
      const int row = c >> 3;        // key within tile
      const int db = (c & 7) * 8;    // d base
      short8 v8 = *(const short8*)(qkv + (size_t)(b * T_SEQ + k0 + row) * TRIPLE +
                                   2 * DM + h * HD + db);
#pragma unroll
      for (int e = 0; e < 8; ++e) Vt[db + e][row] = (u16)v8[e];
    }
    __syncthreads();

    // S = Q K^T : s[nt] covers keys nt*16..+16, rows l4*4..+4
    f32x4 s[4];
#pragma unroll
    for (int nt = 0; nt < 4; ++nt) s[nt] = zero;
#pragma unroll
    for (int kk = 0; kk < 2; ++kk) {
#pragma unroll
      for (int nt = 0; nt < 4; ++nt) {
        int row = nt * 16 + l15;                  // key (local)
        int slot = (kk * 4 + l4) ^ (row & 7);
        short8 kb = *(const short8*)(Ks + row * 128 + slot * 16);
        s[nt] = __builtin_amdgcn_mfma_f32_16x16x32_bf16(qa[kk], kb, s[nt], 0, 0, 0);
      }
    }

    // scale + causal mask (only diagonal tile needs masking)
    const int qbase = q0 + w * 16 + l4 * 4;
#pragma unroll
    for (int nt = 0; nt < 4; ++nt)
#pragma unroll
      for (int r = 0; r < 4; ++r) {
        float v = s[nt][r] * 0.125f;
        if (kt == qt && (k0 + nt * 16 + l15) > (qbase + r)) v = -INFINITY;
        s[nt][r] = v;
      }

    // online softmax: row reductions across 16 lanes (xor 1,2,4,8)
    float mn[4], ps[4], fr[4];
#pragma unroll
    for (int r = 0; r < 4; ++r) {
      float mx = fmaxf(fmaxf(s[0][r], s[1][r]), fmaxf(s[2][r], s[3][r]));
#pragma unroll
      for (int d = 1; d < 16; d <<= 1) mx = fmaxf(mx, __shfl_xor(mx, d));
      mn[r] = fmaxf(mr[r], mx);
      ps[r] = 0.f;
    }
#pragma unroll
    for (int nt = 0; nt < 4; ++nt)
#pragma unroll
      for (int r = 0; r < 4; ++r) {
        float p = __expf(s[nt][r] - mn[r]);
        s[nt][r] = p;
        ps[r] += p;
      }
#pragma unroll
    for (int r = 0; r < 4; ++r) {
#pragma unroll
      for (int d = 1; d < 16; d <<= 1) ps[r] += __shfl_xor(ps[r], d);
      fr[r] = __expf(mr[r] - mn[r]);  // 0 when mr == -inf
      lr[r] = lr[r] * fr[r] + ps[r];
      mr[r] = mn[r];
    }
#pragma unroll
    for (int nt = 0; nt < 4; ++nt)
#pragma unroll
      for (int r = 0; r < 4; ++r) o[nt][r] *= fr[r];

    // P -> per-wave LDS (bf16), then PV MFMA
#pragma unroll
    for (int nt = 0; nt < 4; ++nt)
#pragma unroll
      for (int r = 0; r < 4; ++r) Pl[w][l4 * 4 + r][nt * 16 + l15] = f2bf(s[nt][r]);

#pragma unroll
    for (int kk = 0; kk < 2; ++kk) {
      short8 pa = *(const short8*)(&Pl[w][l15][kk * 32 + l4 * 8]);
#pragma unroll
      for (int nt = 0; nt < 4; ++nt) {
        short8 vb = *(const short8*)(&Vt[nt * 16 + l15][kk * 32 + l4 * 8]);
        o[nt] = __builtin_amdgcn_mfma_f32_16x16x32_bf16(pa, vb, o[nt], 0, 0, 0);
      }
    }
  }

  // normalize + write ctx (bf16) at [b, t, h*64 + d]
#pragma unroll
  for (int nt = 0; nt < 4; ++nt)
#pragma unroll
    for (int r = 0; r < 4; ++r) {
      float val = o[nt][r] / lr[r];
      size_t t = (size_t)(b * T_SEQ + q0 + w * 16 + l4 * 4 + r);
      ctx[t * DM + h * HD + nt * 16 + l15] = f2bf(val);
    }
}

// ---------------------------------------------------------------------------
extern "C" void kernel_launch(void* const* d_in, const int* in_sizes, int n_in,
                              void* d_out, int out_size, void* d_ws, size_t ws_size,
                              hipStream_t stream) {
  const float* x = (const float*)d_in[0];       // [2,2048,1024]
  const float* wqkv = (const float*)d_in[1];    // [3072,1024]
  const float* wout = (const float*)d_in[2];    // [1024,1024]
  float* out = (float*)d_out;                   // [2,2048,1024] f32
  char* ws = (char*)d_ws;

  u16* xb    = (u16*)(ws);                       //  8 MB: 4194304 el
  u16* wqkvb = (u16*)(ws + 8u * 1024 * 1024);    //  6 MB: 3145728 el
  u16* woutb = (u16*)(ws + 14u * 1024 * 1024);   //  2 MB: 1048576 el
  u16* qkvb  = (u16*)(ws + 16u * 1024 * 1024);   // 24 MB: 12582912 el
  u16* ctxb  = (u16*)(ws + 40u * 1024 * 1024);   //  8 MB: 4194304 el

  cast_bf16<<<4096, 256, 0, stream>>>((const float4*)x, (ushort4*)xb, 1048576);
  cast_bf16<<<3072, 256, 0, stream>>>((const float4*)wqkv, (ushort4*)wqkvb, 786432);
  cast_bf16<<<1024, 256, 0, stream>>>((const float4*)wout, (ushort4*)woutb, 262144);

  // qkv[4096][3072] = xb[4096][1024] @ wqkvb[3072][1024]^T
  gemm_bt<u16><<<dim3(24, 32), 256, 0, stream>>>(xb, wqkvb, qkvb, 4096, 3072, 1024);

  // causal attention -> ctx[4096][1024] bf16
  attn_fwd<<<dim3(T_SEQ / 64, N_H, N_B), 256, 0, stream>>>(qkvb, ctxb);

  // out[4096][1024] f32 = ctxb @ woutb^T
  gemm_bt<float><<<dim3(8, 32), 256, 0, stream>>>(ctxb, woutb, out, 4096, 1024, 1024);
}

// Round 2
// 190.281 us; speedup vs baseline: 1.2372x; 1.2372x over previous
//
#include <hip/hip_runtime.h>

// ---------------------------------------------------------------------------
// MultiheadSelfAttention: x[2,2048,1024] f32, w_qkv[3072,1024] f32,
// w_out[1024,1024] f32 -> out[2,2048,1024] f32.
// cast->bf16, qkv = x @ w_qkv^T (MFMA), causal flash attention (swapped-QK,
// double-buffered, swizzled LDS), out = ctx @ w_out^T. fp32 accumulation.
// ---------------------------------------------------------------------------

typedef short short8 __attribute__((ext_vector_type(8)));
typedef float f32x4 __attribute__((ext_vector_type(4)));
typedef unsigned short u16;
typedef unsigned int u32;

#define T_SEQ 2048
#define N_B 2
#define N_H 16
#define HD 64
#define DM 1024
#define TRIPLE 3072

// round-to-nearest-even f32 -> bf16 bits
__device__ __forceinline__ u16 f2bf(float f) {
  union { float f; unsigned u; } v;
  v.f = f;
  unsigned r = v.u + 0x7fffu + ((v.u >> 16) & 1u);
  return (u16)(r >> 16);
}

typedef const __attribute__((address_space(1))) void gvoid;
typedef __attribute__((address_space(3))) void lvoid;

__device__ __forceinline__ void g2l16(const void* g, void* l) {
  __builtin_amdgcn_global_load_lds((gvoid*)g, (lvoid*)l, 16, 0, 0);
}

__device__ __forceinline__ void storeC(float* p, float v) { *p = v; }
__device__ __forceinline__ void storeC(u16* p, float v) { *p = f2bf(v); }

// ---------------------------------------------------------------------------
__global__ __launch_bounds__(256) void cast_bf16(const float4* __restrict__ in,
                                                 ushort4* __restrict__ out, int n4) {
  int i = blockIdx.x * 256 + threadIdx.x;
  if (i < n4) {
    float4 v = in[i];
    ushort4 o;
    o.x = f2bf(v.x); o.y = f2bf(v.y); o.z = f2bf(v.z); o.w = f2bf(v.w);
    out[i] = o;
  }
}

// ---------------------------------------------------------------------------
// C[M][N] = A[M][K] * W[N][K]^T  (bf16 in, fp32 acc). 128x128 tile, BK=64.
// ---------------------------------------------------------------------------
template <typename OutT>
__global__ __launch_bounds__(256) void gemm_bt(const u16* __restrict__ A,
                                               const u16* __restrict__ W,
                                               OutT* __restrict__ C,
                                               int M, int N, int K) {
  __shared__ char As[128 * 64 * 2];
  __shared__ char Bs[128 * 64 * 2];
  const int tid = threadIdx.x;
  const int lane = tid & 63, w = tid >> 6;
  const int l15 = lane & 15, l4 = lane >> 4;
  const int m0 = blockIdx.y * 128, n0 = blockIdx.x * 128;
  const int wr = (w >> 1) * 64, wc = (w & 1) * 64;

  const f32x4 zero = {0.f, 0.f, 0.f, 0.f};
  f32x4 acc[4][4];
#pragma unroll
  for (int m = 0; m < 4; ++m)
#pragma unroll
    for (int n = 0; n < 4; ++n) acc[m][n] = zero;

  for (int k0 = 0; k0 < K; k0 += 64) {
#pragma unroll
    for (int i = 0; i < 4; ++i) {
      const int cb = (i * 4 + w) * 64;
      const int c = cb + lane;
      const int row = c >> 3;
      const int ks = ((c & 7) ^ (row & 7)) * 8;
      g2l16(A + (size_t)(m0 + row) * K + k0 + ks, As + (size_t)cb * 16);
      g2l16(W + (size_t)(n0 + row) * K + k0 + ks, Bs + (size_t)cb * 16);
    }
    __syncthreads();

#pragma unroll
    for (int kk = 0; kk < 2; ++kk) {
      short8 a[4], b[4];
#pragma unroll
      for (int m = 0; m < 4; ++m) {
        int row = wr + m * 16 + l15;
        int slot = (kk * 4 + l4) ^ (row & 7);
        a[m] = *(const short8*)(As + row * 128 + slot * 16);
      }
#pragma unroll
      for (int n = 0; n < 4; ++n) {
        int row = wc + n * 16 + l15;
        int slot = (kk * 4 + l4) ^ (row & 7);
        b[n] = *(const short8*)(Bs + row * 128 + slot * 16);
      }
#pragma unroll
      for (int m = 0; m < 4; ++m)
#pragma unroll
        for (int n = 0; n < 4; ++n)
          acc[m][n] = __builtin_amdgcn_mfma_f32_16x16x32_bf16(a[m], b[n], acc[m][n], 0, 0, 0);
    }
    __syncthreads();
  }

#pragma unroll
  for (int m = 0; m < 4; ++m)
#pragma unroll
    for (int n = 0; n < 4; ++n)
#pragma unroll
      for (int r = 0; r < 4; ++r) {
        int row = m0 + wr + m * 16 + l4 * 4 + r;
        int col = n0 + wc + n * 16 + l15;
        storeC(C + (size_t)row * N + col, acc[m][n][r]);
      }
}

// ---------------------------------------------------------------------------
// Causal flash attention, swapped-QK^T layout, double-buffered K/V tiles.
// Block: 4 waves = 64 q-rows for one (b,h). K-tiles of 64 keys.
// ---------------------------------------------------------------------------
__global__ __launch_bounds__(256) void attn_fwd(const u16* __restrict__ qkv,
                                                u16* __restrict__ ctx) {
  // K tile: rows 128B, 8 slots of 16B; slot j holds k-chunk j^(row&7).
  __shared__ char Ks[2][8192];
  // V^T tile: u16 off = d*64 + ((key>>3 ^ (d&7))<<3) + (key&7)
  __shared__ u16 Vt[2][4096];
  // per-wave P: u16 off = q*64 + ((key>>3 ^ (q&7))<<3) + (key&7)
  __shared__ u16 Pl[4][1024];

  const int tid = threadIdx.x;
  const int lane = tid & 63, w = tid >> 6;
  const int l15 = lane & 15, l4 = lane >> 4;
  const int h = blockIdx.y, b = blockIdx.z;
  const int g = blockIdx.y + N_H * blockIdx.z;
  const int qt = (blockIdx.x + (g & 24)) & 31;   // dither for per-CU balance
  const int q0 = qt * 64;
  const int qrow = q0 + w * 16 + l15;            // this lane's q (softmax row)

  // Q fragment: lane holds Q[q=l15][d = kk*32 + l4*8 .. +8]
  short8 qa[2];
  {
    const u16* qp = qkv + (size_t)(b * T_SEQ + q0 + w * 16 + l15) * TRIPLE + h * HD;
    qa[0] = *(const short8*)(qp + l4 * 8);
    qa[1] = *(const short8*)(qp + 32 + l4 * 8);
  }

  // staging coords
  const int vm = tid & 31;        // key-pair index (keys 2vm, 2vm+1)
  const int vjb = tid >> 5;       // d block (0..7), d = vjb*8 + e
  const size_t vrow0 = (size_t)(b * T_SEQ) * TRIPLE + 2 * DM + h * HD + vjb * 8;

  const f32x4 zero = {0.f, 0.f, 0.f, 0.f};
  f32x4 o[4];
#pragma unroll
  for (int nt = 0; nt < 4; ++nt) o[nt] = zero;
  float mr = -INFINITY, lr = 0.f;
  const float c_log2 = 0.18033688011112042f;  // 0.125 * log2(e)

  short8 v0, v1;

  // --- prologue: stage tile 0 into buf 0 ---
  {
#pragma unroll
    for (int i = 0; i < 2; ++i) {
      const int cb = (i * 4 + w) * 64;
      const int c = cb + lane;
      const int row = c >> 3;
      const int ks = ((c & 7) ^ (row & 7)) * 8;
      g2l16(qkv + (size_t)(b * T_SEQ + row) * TRIPLE + DM + h * HD + ks,
            Ks[0] + (size_t)cb * 16);
    }
    const u16* vp = qkv + vrow0 + (size_t)(2 * vm) * TRIPLE;
    v0 = *(const short8*)vp;
    v1 = *(const short8*)(vp + TRIPLE);
    u32* vt = (u32*)Vt[0];
#pragma unroll
    for (int e = 0; e < 8; ++e) {
      u32 pk = (u32)(u16)v0[e] | ((u32)(u16)v1[e] << 16);
      vt[(vjb * 8 + e) * 32 + (((vm >> 2) ^ e) << 2) + (vm & 3)] = pk;
    }
  }
  __syncthreads();

  for (int kt = 0; kt <= qt; ++kt) {
    const int cur = kt & 1, nxt = cur ^ 1;
    const int k0 = kt * 64;

    // --- prefetch tile kt+1 (async K->LDS, V->regs) ---
    if (kt < qt) {
      const int kn = k0 + 64;
#pragma unroll
      for (int i = 0; i < 2; ++i) {
        const int cb = (i * 4 + w) * 64;
        const int c = cb + lane;
        const int row = c >> 3;
        const int ks = ((c & 7) ^ (row & 7)) * 8;
        g2l16(qkv + (size_t)(b * T_SEQ + kn + row) * TRIPLE + DM + h * HD + ks,
              Ks[nxt] + (size_t)cb * 16);
      }
      const u16* vp = qkv + vrow0 + (size_t)(kn + 2 * vm) * TRIPLE;
      v0 = *(const short8*)vp;
      v1 = *(const short8*)(vp + TRIPLE);
    }

    // --- S^T = K Q^T : lane holds S[key = mt*16 + l4*4 + r][q = l15] ---
    f32x4 s[4];
#pragma unroll
    for (int mt = 0; mt < 4; ++mt) s[mt] = zero;
#pragma unroll
    for (int kk = 0; kk < 2; ++kk) {
#pragma unroll
      for (int mt = 0; mt < 4; ++mt) {
        int row = mt * 16 + l15;
        int slot = (kk * 4 + l4) ^ (row & 7);
        short8 kb = *(const short8*)(Ks[cur] + row * 128 + slot * 16);
        s[mt] = __builtin_amdgcn_mfma_f32_16x16x32_bf16(kb, qa[kk], s[mt], 0, 0, 0);
      }
    }

    // scale (log2 domain) + causal mask (diagonal tile only)
    if (kt == qt) {
#pragma unroll
      for (int mt = 0; mt < 4; ++mt)
#pragma unroll
        for (int r = 0; r < 4; ++r) {
          int key = k0 + mt * 16 + l4 * 4 + r;
          s[mt][r] = (key > qrow) ? -INFINITY : s[mt][r] * c_log2;
        }
    } else {
#pragma unroll
      for (int mt = 0; mt < 4; ++mt)
#pragma unroll
        for (int r = 0; r < 4; ++r) s[mt][r] *= c_log2;
    }

    // --- online softmax: row q=l15 spread over 4 lanes (xor 16, 32) ---
    float mx = -INFINITY;
#pragma unroll
    for (int mt = 0; mt < 4; ++mt)
#pragma unroll
      for (int r = 0; r < 4; ++r) mx = fmaxf(mx, s[mt][r]);
    mx = fmaxf(mx, __shfl_xor(mx, 16));
    mx = fmaxf(mx, __shfl_xor(mx, 32));
    const float mn = fmaxf(mr, mx);
    float ps = 0.f;
#pragma unroll
    for (int mt = 0; mt < 4; ++mt)
#pragma unroll
      for (int r = 0; r < 4; ++r) {
        float p = exp2f(s[mt][r] - mn);
        s[mt][r] = p;
        ps += p;
      }
    ps += __shfl_xor(ps, 16);
    ps += __shfl_xor(ps, 32);
    const float fr = exp2f(mr - mn);
    lr = lr * fr + ps;
    mr = mn;
#pragma unroll
    for (int r = 0; r < 4; ++r) {
      float frq = __shfl(fr, (lane & 48) | (l4 * 4 + r));
#pragma unroll
      for (int nt = 0; nt < 4; ++nt) o[nt][r] *= frq;
    }

    // --- P -> per-wave LDS (bf16, swizzled, u32-paired) ---
    {
      u32* pl = (u32*)Pl[w];
#pragma unroll
      for (int mt = 0; mt < 4; ++mt)
#pragma unroll
        for (int sp = 0; sp < 2; ++sp) {
          int key = mt * 16 + l4 * 4 + 2 * sp;
          u32 pk = (u32)f2bf(s[mt][2 * sp]) | ((u32)f2bf(s[mt][2 * sp + 1]) << 16);
          int slot = ((key >> 3) ^ (l15 & 7));
          pl[l15 * 32 + slot * 4 + ((key & 7) >> 1)] = pk;
        }
    }

    // --- PV: o[q][d] += P[q][key] * V^T[d][key] ---
#pragma unroll
    for (int kk = 0; kk < 2; ++kk) {
      short8 pa = *(const short8*)(Pl[w] + l15 * 64 + (((kk * 4 + l4) ^ (l15 & 7)) << 3));
#pragma unroll
      for (int nt = 0; nt < 4; ++nt) {
        int d = nt * 16 + l15;
        short8 vb = *(const short8*)(Vt[cur] + d * 64 + (((kk * 4 + l4) ^ (l15 & 7)) << 3));
        o[nt] = __builtin_amdgcn_mfma_f32_16x16x32_bf16(pa, vb, o[nt], 0, 0, 0);
      }
    }

    // --- scatter prefetched V regs into Vt[nxt] (vmcnt waits on v0/v1) ---
    if (kt < qt) {
      u32* vt = (u32*)Vt[nxt];
#pragma unroll
      for (int e = 0; e < 8; ++e) {
        u32 pk = (u32)(u16)v0[e] | ((u32)(u16)v1[e] << 16);
        vt[(vjb * 8 + e) * 32 + (((vm >> 2) ^ e) << 2) + (vm & 3)] = pk;
      }
    }
    __syncthreads();
  }

  // --- normalize + write ctx ---
#pragma unroll
  for (int r = 0; r < 4; ++r) {
    float lrq = __shfl(lr, (lane & 48) | (l4 * 4 + r));
    float inv = __builtin_amdgcn_rcpf(lrq);
#pragma unroll
    for (int nt = 0; nt < 4; ++nt) {
      size_t t = (size_t)(b * T_SEQ + q0 + w * 16 + l4 * 4 + r);
      ctx[t * DM + h * HD + nt * 16 + l15] = f2bf(o[nt][r] * inv);
    }
  }
}

// ---------------------------------------------------------------------------
extern "C" void kernel_launch(void* const* d_in, const int* in_sizes, int n_in,
                              void* d_out, int out_size, void* d_ws, size_t ws_size,
                              hipStream_t stream) {
  const float* x = (const float*)d_in[0];
  const float* wqkv = (const float*)d_in[1];
  const float* wout = (const float*)d_in[2];
  float* out = (float*)d_out;
  char* ws = (char*)d_ws;

  u16* xb    = (u16*)(ws);
  u16* wqkvb = (u16*)(ws + 8u * 1024 * 1024);
  u16* woutb = (u16*)(ws + 14u * 1024 * 1024);
  u16* qkvb  = (u16*)(ws + 16u * 1024 * 1024);
  u16* ctxb  = (u16*)(ws + 40u * 1024 * 1024);

  cast_bf16<<<4096, 256, 0, stream>>>((const float4*)x, (ushort4*)xb, 1048576);
  cast_bf16<<<3072, 256, 0, stream>>>((const float4*)wqkv, (ushort4*)wqkvb, 786432);
  cast_bf16<<<1024, 256, 0, stream>>>((const float4*)wout, (ushort4*)woutb, 262144);

  gemm_bt<u16><<<dim3(24, 32), 256, 0, stream>>>(xb, wqkvb, qkvb, 4096, 3072, 1024);

  attn_fwd<<<dim3(T_SEQ / 64, N_H, N_B), 256, 0, stream>>>(qkvb, ctxb);

  gemm_bt<float><<<dim3(8, 32), 256, 0, stream>>>(ctxb, woutb, out, 4096, 1024, 1024);
}

// Round 3
// 149.072 us; speedup vs baseline: 1.5792x; 1.2764x over previous
//
#include <hip/hip_runtime.h>

// ---------------------------------------------------------------------------
// MultiheadSelfAttention: x[2,2048,1024] f32, w_qkv[3072,1024] f32,
// w_out[1024,1024] f32 -> out[2,2048,1024] f32.
// cast->bf16, qkv = x @ w_qkv^T (MFMA), causal flash attention (2-wave blocks,
// reg-prefetch single-buffer LDS, swapped-QK, defer-max), out = ctx @ w_out^T.
// ---------------------------------------------------------------------------

typedef short short8 __attribute__((ext_vector_type(8)));
typedef float f32x4 __attribute__((ext_vector_type(4)));
typedef unsigned short u16;
typedef unsigned int u32;

#define T_SEQ 2048
#define N_B 2
#define N_H 16
#define HD 64
#define DM 1024
#define TRIPLE 3072

__device__ __forceinline__ u16 f2bf(float f) {
  union { float f; unsigned u; } v;
  v.f = f;
  unsigned r = v.u + 0x7fffu + ((v.u >> 16) & 1u);
  return (u16)(r >> 16);
}

__device__ __forceinline__ float bf2f(u16 x) {
  return __uint_as_float((u32)x << 16);
}

// v_cvt_pk_bf16_f32: lo = bf16(a), hi = bf16(b), one instruction
__device__ __forceinline__ u32 cvtpk(float a, float b) {
  u32 r;
  asm("v_cvt_pk_bf16_f32 %0, %1, %2" : "=v"(r) : "v"(a), "v"(b));
  return r;
}

typedef const __attribute__((address_space(1))) void gvoid;
typedef __attribute__((address_space(3))) void lvoid;

__device__ __forceinline__ void g2l16(const void* g, void* l) {
  __builtin_amdgcn_global_load_lds((gvoid*)g, (lvoid*)l, 16, 0, 0);
}

__device__ __forceinline__ void storeC(float* p, float v) { *p = v; }
__device__ __forceinline__ void storeC(u16* p, float v) { *p = f2bf(v); }

// ---------------------------------------------------------------------------
// fused cast of x | w_qkv | w_out into contiguous bf16 workspace
__global__ __launch_bounds__(256) void cast_all(const float4* __restrict__ x,
                                                const float4* __restrict__ wq,
                                                const float4* __restrict__ wo,
                                                ushort4* __restrict__ out) {
  int i = blockIdx.x * 256 + threadIdx.x;  // 0 .. 2097151
  const float4* src;
  int off;
  if (i < 1048576) { src = x; off = 0; }
  else if (i < 1835008) { src = wq; off = 1048576; }
  else { src = wo; off = 1835008; }
  float4 v = src[i - off];
  ushort4 o;
  o.x = f2bf(v.x); o.y = f2bf(v.y); o.z = f2bf(v.z); o.w = f2bf(v.w);
  out[i] = o;
}

// ---------------------------------------------------------------------------
// C[M][N] = A[M][K] * W[N][K]^T  (bf16 in, fp32 acc). 128x128 tile, BK=64.
// ---------------------------------------------------------------------------
template <typename OutT>
__global__ __launch_bounds__(256) void gemm_bt(const u16* __restrict__ A,
                                               const u16* __restrict__ W,
                                               OutT* __restrict__ C,
                                               int M, int N, int K) {
  __shared__ char As[128 * 64 * 2];
  __shared__ char Bs[128 * 64 * 2];
  const int tid = threadIdx.x;
  const int lane = tid & 63, w = tid >> 6;
  const int l15 = lane & 15, l4 = lane >> 4;
  const int m0 = blockIdx.y * 128, n0 = blockIdx.x * 128;
  const int wr = (w >> 1) * 64, wc = (w & 1) * 64;

  const f32x4 zero = {0.f, 0.f, 0.f, 0.f};
  f32x4 acc[4][4];
#pragma unroll
  for (int m = 0; m < 4; ++m)
#pragma unroll
    for (int n = 0; n < 4; ++n) acc[m][n] = zero;

  for (int k0 = 0; k0 < K; k0 += 64) {
#pragma unroll
    for (int i = 0; i < 4; ++i) {
      const int cb = (i * 4 + w) * 64;
      const int c = cb + lane;
      const int row = c >> 3;
      const int ks = ((c & 7) ^ (row & 7)) * 8;
      g2l16(A + (size_t)(m0 + row) * K + k0 + ks, As + (size_t)cb * 16);
      g2l16(W + (size_t)(n0 + row) * K + k0 + ks, Bs + (size_t)cb * 16);
    }
    __syncthreads();

#pragma unroll
    for (int kk = 0; kk < 2; ++kk) {
      short8 a[4], b[4];
#pragma unroll
      for (int m = 0; m < 4; ++m) {
        int row = wr + m * 16 + l15;
        int slot = (kk * 4 + l4) ^ (row & 7);
        a[m] = *(const short8*)(As + row * 128 + slot * 16);
      }
#pragma unroll
      for (int n = 0; n < 4; ++n) {
        int row = wc + n * 16 + l15;
        int slot = (kk * 4 + l4) ^ (row & 7);
        b[n] = *(const short8*)(Bs + row * 128 + slot * 16);
      }
#pragma unroll
      for (int m = 0; m < 4; ++m)
#pragma unroll
        for (int n = 0; n < 4; ++n)
          acc[m][n] = __builtin_amdgcn_mfma_f32_16x16x32_bf16(a[m], b[n], acc[m][n], 0, 0, 0);
    }
    __syncthreads();
  }

#pragma unroll
  for (int m = 0; m < 4; ++m)
#pragma unroll
    for (int n = 0; n < 4; ++n)
#pragma unroll
      for (int r = 0; r < 4; ++r) {
        int row = m0 + wr + m * 16 + l4 * 4 + r;
        int col = n0 + wc + n * 16 + l15;
        storeC(C + (size_t)row * N + col, acc[m][n][r]);
      }
}

// ---------------------------------------------------------------------------
// Causal flash attention. 2-wave blocks, 32 q-rows/block (16/wave).
// Single-buffered K/V/P LDS (20.5 KB) + register prefetch of tile t+1.
// ---------------------------------------------------------------------------
__global__ __launch_bounds__(128) void attn_fwd(const u16* __restrict__ qkv,
                                                u16* __restrict__ ctx) {
  __shared__ char Ks[8192];      // K tile [64 key][128B], slot c^(row&7)
  __shared__ u16 Vt[4096];       // V^T: byte = d*128 + slot*16, slot=(key>>3)^(d&7)^((d>>3)&3)
  __shared__ char Pl[2][2048];   // per-wave P [16 q][64 key] swizzled

  const int tid = threadIdx.x;
  const int lane = tid & 63, w = tid >> 6;
  const int l15 = lane & 15, l4 = lane >> 4;
  const int h = blockIdx.y, b = blockIdx.z;
  const int g = h + N_H * b;
  const int qt = (blockIdx.x + 9 * g) & 63;     // dither for CU balance
  const int q0 = qt * 32;
  const int qrow = q0 + w * 16 + l15;           // softmax row of this lane
  const int ktmax = (q0 + 31) >> 6;             // inclusive last tile

  // ---- load + prescale Q by 0.125*log2(e) ----
  const float c_log2 = 0.18033688011112042f;
  short8 qa[2];
  {
    const u16* qp = qkv + (size_t)(b * T_SEQ + q0 + w * 16 + l15) * TRIPLE + h * HD;
#pragma unroll
    for (int kk = 0; kk < 2; ++kk) {
      short8 raw = *(const short8*)(qp + kk * 32 + l4 * 8);
      union { short8 v; u32 w4[4]; } qq;
#pragma unroll
      for (int j = 0; j < 4; ++j)
        qq.w4[j] = cvtpk(bf2f((u16)raw[2 * j]) * c_log2,
                         bf2f((u16)raw[2 * j + 1]) * c_log2);
      qa[kk] = qq.v;
    }
  }

  // ---- staging coordinates ----
  const int krow = tid >> 3;           // K row (+16*i), const slot per thread
  const int kc = tid & 7;
  const int kslot = kc ^ (krow & 7);
  const size_t kgbase = (size_t)(b * T_SEQ) * TRIPLE + DM + h * HD + kc * 8;

  const int kq = tid & 15;             // V: keys 4kq..4kq+3
  const int vjb = tid >> 4;            // d-block 0..7
  const size_t vgbase = (size_t)(b * T_SEQ) * TRIPLE + 2 * DM + h * HD + vjb * 8;

  char* Plb = Pl[w];

  const f32x4 zero = {0.f, 0.f, 0.f, 0.f};
  f32x4 o[4];
#pragma unroll
  for (int nt = 0; nt < 4; ++nt) o[nt] = zero;
  float mr = -INFINITY, lr = 0.f;

  short8 kst[4], vr[4];

  // ---- prologue: load + scatter tile 0 ----
#pragma unroll
  for (int i = 0; i < 4; ++i)
    kst[i] = *(const short8*)(qkv + kgbase + (size_t)(krow + 16 * i) * TRIPLE);
#pragma unroll
  for (int j = 0; j < 4; ++j)
    vr[j] = *(const short8*)(qkv + vgbase + (size_t)(4 * kq + j) * TRIPLE);
#pragma unroll
  for (int i = 0; i < 4; ++i)
    *(short8*)(Ks + (krow + 16 * i) * 128 + (kslot << 4)) = kst[i];
#pragma unroll
  for (int e = 0; e < 8; ++e) {
    int d = vjb * 8 + e;
    int slot = (kq >> 1) ^ e ^ (vjb & 3);
    uint2 pk;
    pk.x = (u32)(u16)vr[0][e] | ((u32)(u16)vr[1][e] << 16);
    pk.y = (u32)(u16)vr[2][e] | ((u32)(u16)vr[3][e] << 16);
    *(uint2*)((char*)Vt + d * 128 + slot * 16 + ((kq & 1) << 3)) = pk;
  }
  __syncthreads();

  for (int kt = 0;; ++kt) {
    const int k0 = kt * 64;

    // ---- issue prefetch of tile kt+1 into registers ----
    if (kt < ktmax) {
      const int kn = k0 + 64;
#pragma unroll
      for (int i = 0; i < 4; ++i)
        kst[i] = *(const short8*)(qkv + kgbase + (size_t)(kn + krow + 16 * i) * TRIPLE);
#pragma unroll
      for (int j = 0; j < 4; ++j)
        vr[j] = *(const short8*)(qkv + vgbase + (size_t)(kn + 4 * kq + j) * TRIPLE);
    }

    // ---- S^T = K Q^T : lane holds S[key=mt*16+l4*4+r][q=l15] ----
    f32x4 s[4];
#pragma unroll
    for (int mt = 0; mt < 4; ++mt) s[mt] = zero;
#pragma unroll
    for (int kk = 0; kk < 2; ++kk) {
#pragma unroll
      for (int mt = 0; mt < 4; ++mt) {
        int row = mt * 16 + l15;
        int slot = (kk * 4 + l4) ^ (row & 7);
        short8 kb = *(const short8*)(Ks + row * 128 + slot * 16);
        s[mt] = __builtin_amdgcn_mfma_f32_16x16x32_bf16(kb, qa[kk], s[mt], 0, 0, 0);
      }
    }

    // causal mask on diagonal tile (Q pre-scaled, S already in log2 units)
    if (kt == ktmax) {
#pragma unroll
      for (int mt = 0; mt < 4; ++mt)
#pragma unroll
        for (int r = 0; r < 4; ++r) {
          int key = k0 + mt * 16 + l4 * 4 + r;
          if (key > qrow) s[mt][r] = -INFINITY;
        }
    }

    // ---- online softmax, defer-max (THR = 8 in log2 units) ----
    float mx = fmaxf(fmaxf(fmaxf(s[0][0], s[0][1]), fmaxf(s[0][2], s[0][3])),
                     fmaxf(fmaxf(s[1][0], s[1][1]), fmaxf(s[1][2], s[1][3])));
    mx = fmaxf(mx, fmaxf(fmaxf(fmaxf(s[2][0], s[2][1]), fmaxf(s[2][2], s[2][3])),
                         fmaxf(fmaxf(s[3][0], s[3][1]), fmaxf(s[3][2], s[3][3]))));
    mx = fmaxf(mx, __shfl_xor(mx, 16));
    mx = fmaxf(mx, __shfl_xor(mx, 32));
    if (!__all(mx - mr <= 8.0f)) {
      float mn = fmaxf(mr, mx);
      float fr = exp2f(mr - mn);   // 0 on first tile
      lr *= fr;
#pragma unroll
      for (int r = 0; r < 4; ++r) {
        float frq = __shfl(fr, l4 * 4 + r);
#pragma unroll
        for (int nt = 0; nt < 4; ++nt) o[nt][r] *= frq;
      }
      mr = mn;
    }
    float ps = 0.f;
#pragma unroll
    for (int mt = 0; mt < 4; ++mt)
#pragma unroll
      for (int r = 0; r < 4; ++r) {
        float p = exp2f(s[mt][r] - mr);
        s[mt][r] = p;
        ps += p;
      }
    lr += ps;   // per-lane partial; reduced at epilogue

    // ---- P -> per-wave LDS (cvt_pk + b64 writes) ----
#pragma unroll
    for (int mt = 0; mt < 4; ++mt) {
      uint2 pw;
      pw.x = cvtpk(s[mt][0], s[mt][1]);
      pw.y = cvtpk(s[mt][2], s[mt][3]);
      int slot = ((mt * 2 + (l4 >> 1)) ^ (l15 & 7));
      *(uint2*)(Plb + l15 * 128 + (slot << 4) + ((l4 & 1) << 3)) = pw;
    }

    // ---- PV: o[q][d] += P[q][key] * V[key][d] ----
#pragma unroll
    for (int kk = 0; kk < 2; ++kk) {
      short8 pa = *(const short8*)(Plb + l15 * 128 + (((kk * 4 + l4) ^ (l15 & 7)) << 4));
#pragma unroll
      for (int nt = 0; nt < 4; ++nt) {
        int d = nt * 16 + l15;
        int slot = (kk * 4 + l4) ^ (l15 & 7) ^ ((nt * 2 + (l15 >> 3)) & 3);
        short8 vb = *(const short8*)((char*)Vt + d * 128 + slot * 16);
        o[nt] = __builtin_amdgcn_mfma_f32_16x16x32_bf16(pa, vb, o[nt], 0, 0, 0);
      }
    }

    if (kt == ktmax) break;

    // ---- scatter prefetched tile (vmcnt waits inserted by compiler) ----
    __syncthreads();   // all waves done reading Ks/Vt of tile kt
#pragma unroll
    for (int i = 0; i < 4; ++i)
      *(short8*)(Ks + (krow + 16 * i) * 128 + (kslot << 4)) = kst[i];
#pragma unroll
    for (int e = 0; e < 8; ++e) {
      int d = vjb * 8 + e;
      int slot = (kq >> 1) ^ e ^ (vjb & 3);
      uint2 pk;
      pk.x = (u32)(u16)vr[0][e] | ((u32)(u16)vr[1][e] << 16);
      pk.y = (u32)(u16)vr[2][e] | ((u32)(u16)vr[3][e] << 16);
      *(uint2*)((char*)Vt + d * 128 + slot * 16 + ((kq & 1) << 3)) = pk;
    }
    __syncthreads();   // writes visible for next iteration
  }

  // ---- epilogue: reduce lr, normalize, write ctx ----
  lr += __shfl_xor(lr, 16);
  lr += __shfl_xor(lr, 32);
#pragma unroll
  for (int r = 0; r < 4; ++r) {
    float lrq = __shfl(lr, l4 * 4 + r);
    float inv = __builtin_amdgcn_rcpf(lrq);
    size_t t = (size_t)(b * T_SEQ + q0 + w * 16 + l4 * 4 + r);
#pragma unroll
    for (int nt = 0; nt < 4; ++nt)
      ctx[t * DM + h * HD + nt * 16 + l15] = f2bf(o[nt][r] * inv);
  }
}

// ---------------------------------------------------------------------------
extern "C" void kernel_launch(void* const* d_in, const int* in_sizes, int n_in,
                              void* d_out, int out_size, void* d_ws, size_t ws_size,
                              hipStream_t stream) {
  const float* x = (const float*)d_in[0];
  const float* wqkv = (const float*)d_in[1];
  const float* wout = (const float*)d_in[2];
  float* out = (float*)d_out;
  char* ws = (char*)d_ws;

  u16* xb    = (u16*)(ws);                       // 8 MB
  u16* wqkvb = (u16*)(ws + 8u * 1024 * 1024);    // 6 MB
  u16* woutb = (u16*)(ws + 14u * 1024 * 1024);   // 2 MB
  u16* qkvb  = (u16*)(ws + 16u * 1024 * 1024);   // 24 MB
  u16* ctxb  = (u16*)(ws + 40u * 1024 * 1024);   // 8 MB

  cast_all<<<8192, 256, 0, stream>>>((const float4*)x, (const float4*)wqkv,
                                     (const float4*)wout, (ushort4*)xb);

  gemm_bt<u16><<<dim3(24, 32), 256, 0, stream>>>(xb, wqkvb, qkvb, 4096, 3072, 1024);

  attn_fwd<<<dim3(64, N_H, N_B), 128, 0, stream>>>(qkvb, ctxb);

  gemm_bt<float><<<dim3(8, 32), 256, 0, stream>>>(ctxb, woutb, out, 4096, 1024, 1024);
}

// Round 4
// 135.518 us; speedup vs baseline: 1.7372x; 1.1000x over previous
//
#include <hip/hip_runtime.h>

// ---------------------------------------------------------------------------
// MultiheadSelfAttention: x[2,2048,1024] f32, w_qkv[3072,1024] f32,
// w_out[1024,1024] f32 -> out[2,2048,1024] f32.
// cast->bf16, qkv = x @ w_qkv^T (MFMA), V pre-transpose, causal flash attn
// (4-wave blocks, double-buffered K/V via global_load_lds, swapped-QK,
// defer-max), out = ctx @ w_out^T. fp32 accumulation.
// ---------------------------------------------------------------------------

typedef short short8 __attribute__((ext_vector_type(8)));
typedef float f32x4 __attribute__((ext_vector_type(4)));
typedef unsigned short u16;
typedef unsigned int u32;

#define T_SEQ 2048
#define N_B 2
#define N_H 16
#define HD 64
#define DM 1024
#define TRIPLE 3072

__device__ __forceinline__ u16 f2bf(float f) {
  union { float f; unsigned u; } v;
  v.f = f;
  unsigned r = v.u + 0x7fffu + ((v.u >> 16) & 1u);
  return (u16)(r >> 16);
}

__device__ __forceinline__ float bf2f(u16 x) {
  return __uint_as_float((u32)x << 16);
}

__device__ __forceinline__ u32 cvtpk(float a, float b) {
  u32 r;
  asm("v_cvt_pk_bf16_f32 %0, %1, %2" : "=v"(r) : "v"(a), "v"(b));
  return r;
}

typedef const __attribute__((address_space(1))) void gvoid;
typedef __attribute__((address_space(3))) void lvoid;

__device__ __forceinline__ void g2l16(const void* g, void* l) {
  __builtin_amdgcn_global_load_lds((gvoid*)g, (lvoid*)l, 16, 0, 0);
}

__device__ __forceinline__ void storeC(float* p, float v) { *p = v; }
__device__ __forceinline__ void storeC(u16* p, float v) { *p = f2bf(v); }

// ---------------------------------------------------------------------------
// fused cast of x | w_qkv | w_out into contiguous bf16 workspace
__global__ __launch_bounds__(256) void cast_all(const float4* __restrict__ x,
                                                const float4* __restrict__ wq,
                                                const float4* __restrict__ wo,
                                                ushort4* __restrict__ out) {
  int i = blockIdx.x * 256 + threadIdx.x;
  const float4* src;
  int off;
  if (i < 1048576) { src = x; off = 0; }
  else if (i < 1835008) { src = wq; off = 1048576; }
  else { src = wo; off = 1835008; }
  float4 v = src[i - off];
  ushort4 o;
  o.x = f2bf(v.x); o.y = f2bf(v.y); o.z = f2bf(v.z); o.w = f2bf(v.w);
  out[i] = o;
}

// ---------------------------------------------------------------------------
// V transpose: qkv[b*T+t][2048 + h*64 + d] -> vT[(b*16+h)*64 + d][t] (bf16).
// Per thread: 8x8 u16 in-register transpose; coalesced reads and writes.
// ---------------------------------------------------------------------------
__global__ __launch_bounds__(256) void vtrans(const u16* __restrict__ qkv,
                                              u16* __restrict__ vT) {
  const int tid = threadIdx.x;
  const int w = tid >> 6, lane = tid & 63;
  const int ti = lane >> 3, di = lane & 7;
  const int h = blockIdx.y, b = blockIdx.z;
  const int t0 = blockIdx.x * 256 + w * 64 + ti * 8;

  const u16* src = qkv + (size_t)(b * T_SEQ + t0) * TRIPLE + 2 * DM + h * HD + di * 8;
  u32 x[8][4];
#pragma unroll
  for (int e = 0; e < 8; ++e) {
    union { short8 v; u32 u[4]; } cv;
    cv.v = *(const short8*)(src + (size_t)e * TRIPLE);
#pragma unroll
    for (int j = 0; j < 4; ++j) x[e][j] = cv.u[j];
  }
  // 16-bit transpose of 2x2 blocks: y[2a+(d&1)][j] = col d=2j+(d&1), t-pair a
  u32 y[8][4];
#pragma unroll
  for (int a = 0; a < 4; ++a)
#pragma unroll
    for (int j = 0; j < 4; ++j) {
      u32 lo = x[2 * a][j], hi = x[2 * a + 1][j];
      y[2 * a][j] = (lo & 0x0000FFFFu) | (hi << 16);
      y[2 * a + 1][j] = (lo >> 16) | (hi & 0xFFFF0000u);
    }
  // u32-level gather (free renaming): out row dd, t-pair a = y[2a+(dd&1)][dd>>1]
  u16* dst = vT + ((size_t)(b * N_H + h) * HD + di * 8) * T_SEQ + t0;
#pragma unroll
  for (int dd = 0; dd < 8; ++dd) {
    union { short8 v; u32 u[4]; } cv;
#pragma unroll
    for (int a = 0; a < 4; ++a) cv.u[a] = y[2 * a + (dd & 1)][dd >> 1];
    *(short8*)(dst + (size_t)dd * T_SEQ) = cv.v;
  }
}

// ---------------------------------------------------------------------------
// C[M][N] = A[M][K] * W[N][K]^T  (bf16 in, fp32 acc). 128x128 tile, BK=64.
// ---------------------------------------------------------------------------
template <typename OutT>
__global__ __launch_bounds__(256) void gemm_bt(const u16* __restrict__ A,
                                               const u16* __restrict__ W,
                                               OutT* __restrict__ C,
                                               int M, int N, int K) {
  __shared__ char As[128 * 64 * 2];
  __shared__ char Bs[128 * 64 * 2];
  const int tid = threadIdx.x;
  const int lane = tid & 63, w = tid >> 6;
  const int l15 = lane & 15, l4 = lane >> 4;
  const int m0 = blockIdx.y * 128, n0 = blockIdx.x * 128;
  const int wr = (w >> 1) * 64, wc = (w & 1) * 64;

  const f32x4 zero = {0.f, 0.f, 0.f, 0.f};
  f32x4 acc[4][4];
#pragma unroll
  for (int m = 0; m < 4; ++m)
#pragma unroll
    for (int n = 0; n < 4; ++n) acc[m][n] = zero;

  for (int k0 = 0; k0 < K; k0 += 64) {
#pragma unroll
    for (int i = 0; i < 4; ++i) {
      const int cb = (i * 4 + w) * 64;
      const int c = cb + lane;
      const int row = c >> 3;
      const int ks = ((c & 7) ^ (row & 7)) * 8;
      g2l16(A + (size_t)(m0 + row) * K + k0 + ks, As + (size_t)cb * 16);
      g2l16(W + (size_t)(n0 + row) * K + k0 + ks, Bs + (size_t)cb * 16);
    }
    __syncthreads();

#pragma unroll
    for (int kk = 0; kk < 2; ++kk) {
      short8 a[4], b[4];
#pragma unroll
      for (int m = 0; m < 4; ++m) {
        int row = wr + m * 16 + l15;
        int slot = (kk * 4 + l4) ^ (row & 7);
        a[m] = *(const short8*)(As + row * 128 + slot * 16);
      }
#pragma unroll
      for (int n = 0; n < 4; ++n) {
        int row = wc + n * 16 + l15;
        int slot = (kk * 4 + l4) ^ (row & 7);
        b[n] = *(const short8*)(Bs + row * 128 + slot * 16);
      }
#pragma unroll
      for (int m = 0; m < 4; ++m)
#pragma unroll
        for (int n = 0; n < 4; ++n)
          acc[m][n] = __builtin_amdgcn_mfma_f32_16x16x32_bf16(a[m], b[n], acc[m][n], 0, 0, 0);
    }
    __syncthreads();
  }

#pragma unroll
  for (int m = 0; m < 4; ++m)
#pragma unroll
    for (int n = 0; n < 4; ++n)
#pragma unroll
      for (int r = 0; r < 4; ++r) {
        int row = m0 + wr + m * 16 + l4 * 4 + r;
        int col = n0 + wc + n * 16 + l15;
        storeC(C + (size_t)row * N + col, acc[m][n][r]);
      }
}

// ---------------------------------------------------------------------------
// Causal flash attention. 4 waves = 64 q-rows/block. K/V^T double-buffered in
// LDS, staged purely by global_load_lds (pre-swizzled source). 1 barrier/iter.
// ---------------------------------------------------------------------------
__global__ __launch_bounds__(256) void attn_fwd(const u16* __restrict__ qkv,
                                                const u16* __restrict__ vT,
                                                u16* __restrict__ ctx) {
  __shared__ char Ks[2][8192];   // K tile [64 key][8 slots x 16B], slot=c^(row&7)
  __shared__ char Vs[2][8192];   // V^T tile [64 d][8 slots x 16B], slot=c^(d&7)
  __shared__ char Pl[4][2048];   // per-wave P [16 q][64 key], swizzled

  const int tid = threadIdx.x;
  const int lane = tid & 63, w = tid >> 6;
  const int l15 = lane & 15, l4 = lane >> 4;
  const int h = blockIdx.y, b = blockIdx.z;
  const int g = h + N_H * b;                  // == b*16+h
  const int qt = (blockIdx.x + 9 * g) & 31;   // dither for CU balance
  const int q0 = qt * 64;
  const int qrow = q0 + w * 16 + l15;
  const int ktmax = qt;

  // ---- Q load + prescale by 0.125*log2(e) ----
  const float c_log2 = 0.18033688011112042f;
  short8 qa[2];
  {
    const u16* qp = qkv + (size_t)(b * T_SEQ + q0 + w * 16 + l15) * TRIPLE + h * HD;
#pragma unroll
    for (int kk = 0; kk < 2; ++kk) {
      short8 raw = *(const short8*)(qp + kk * 32 + l4 * 8);
      union { short8 v; u32 w4[4]; } qq;
#pragma unroll
      for (int j = 0; j < 4; ++j)
        qq.w4[j] = cvtpk(bf2f((u16)raw[2 * j]) * c_log2,
                         bf2f((u16)raw[2 * j + 1]) * c_log2);
      qa[kk] = qq.v;
    }
  }

  // ---- staging pointers (pre-swizzled source, linear LDS dest) ----
  const int r0 = tid >> 3, c0 = tid & 7;
  const u16* kptr0 = qkv + (size_t)(b * T_SEQ + r0) * TRIPLE + DM + h * HD +
                     ((c0 ^ (r0 & 7)) << 3);
  const u16* kptr1 = kptr0 + (size_t)32 * TRIPLE;
  const u16* vptr0 = vT + ((size_t)g * HD + r0) * T_SEQ + ((c0 ^ (r0 & 7)) << 3);
  const u16* vptr1 = vptr0 + (size_t)32 * T_SEQ;

  char* Plb = Pl[w];

  const f32x4 zero = {0.f, 0.f, 0.f, 0.f};
  f32x4 o[4];
#pragma unroll
  for (int nt = 0; nt < 4; ++nt) o[nt] = zero;
  float mr = -INFINITY, lr = 0.f;

  // ---- prologue: stage tile 0 into buf 0 ----
  g2l16(kptr0, Ks[0] + tid * 16);
  g2l16(kptr1, Ks[0] + (256 + tid) * 16);
  g2l16(vptr0, Vs[0] + tid * 16);
  g2l16(vptr1, Vs[0] + (256 + tid) * 16);
  kptr0 += (size_t)64 * TRIPLE; kptr1 += (size_t)64 * TRIPLE;
  vptr0 += 64; vptr1 += 64;
  __syncthreads();

  for (int kt = 0;; ++kt) {
    const int cur = kt & 1;
    const int k0 = kt * 64;

    // ---- issue prefetch of tile kt+1 into buf cur^1 ----
    if (kt < ktmax) {
      g2l16(kptr0, Ks[cur ^ 1] + tid * 16);
      g2l16(kptr1, Ks[cur ^ 1] + (256 + tid) * 16);
      g2l16(vptr0, Vs[cur ^ 1] + tid * 16);
      g2l16(vptr1, Vs[cur ^ 1] + (256 + tid) * 16);
      kptr0 += (size_t)64 * TRIPLE; kptr1 += (size_t)64 * TRIPLE;
      vptr0 += 64; vptr1 += 64;
    }

    // ---- S^T = K Q^T : lane holds S[key=mt*16+l4*4+r][q=l15] ----
    f32x4 s[4];
#pragma unroll
    for (int mt = 0; mt < 4; ++mt) s[mt] = zero;
#pragma unroll
    for (int kk = 0; kk < 2; ++kk) {
#pragma unroll
      for (int mt = 0; mt < 4; ++mt) {
        int row = mt * 16 + l15;
        int slot = (kk * 4 + l4) ^ (row & 7);
        short8 kb = *(const short8*)(Ks[cur] + row * 128 + slot * 16);
        s[mt] = __builtin_amdgcn_mfma_f32_16x16x32_bf16(kb, qa[kk], s[mt], 0, 0, 0);
      }
    }

    // causal mask on diagonal tile (Q pre-scaled; S already in log2 units)
    if (kt == ktmax) {
#pragma unroll
      for (int mt = 0; mt < 4; ++mt)
#pragma unroll
        for (int r = 0; r < 4; ++r) {
          int key = k0 + mt * 16 + l4 * 4 + r;
          if (key > qrow) s[mt][r] = -INFINITY;
        }
    }

    // ---- online softmax, defer-max (THR = 8 in log2 units) ----
    float mx = fmaxf(fmaxf(fmaxf(s[0][0], s[0][1]), fmaxf(s[0][2], s[0][3])),
                     fmaxf(fmaxf(s[1][0], s[1][1]), fmaxf(s[1][2], s[1][3])));
    mx = fmaxf(mx, fmaxf(fmaxf(fmaxf(s[2][0], s[2][1]), fmaxf(s[2][2], s[2][3])),
                         fmaxf(fmaxf(s[3][0], s[3][1]), fmaxf(s[3][2], s[3][3]))));
    mx = fmaxf(mx, __shfl_xor(mx, 16));
    mx = fmaxf(mx, __shfl_xor(mx, 32));
    if (!__all(mx - mr <= 8.0f)) {
      float mn = fmaxf(mr, mx);
      float fr = exp2f(mr - mn);   // 0 on first tile
      lr *= fr;
#pragma unroll
      for (int r = 0; r < 4; ++r) {
        float frq = __shfl(fr, l4 * 4 + r);
#pragma unroll
        for (int nt = 0; nt < 4; ++nt) o[nt][r] *= frq;
      }
      mr = mn;
    }
    float ps = 0.f;
#pragma unroll
    for (int mt = 0; mt < 4; ++mt)
#pragma unroll
      for (int r = 0; r < 4; ++r) {
        float p = exp2f(s[mt][r] - mr);
        s[mt][r] = p;
        ps += p;
      }
    lr += ps;   // per-lane partial; reduced at epilogue

    // ---- P -> per-wave LDS (cvt_pk + b64 writes) ----
#pragma unroll
    for (int mt = 0; mt < 4; ++mt) {
      uint2 pw;
      pw.x = cvtpk(s[mt][0], s[mt][1]);
      pw.y = cvtpk(s[mt][2], s[mt][3]);
      int slot = ((mt * 2 + (l4 >> 1)) ^ (l15 & 7));
      *(uint2*)(Plb + l15 * 128 + (slot << 4) + ((l4 & 1) << 3)) = pw;
    }

    // ---- PV: o[q][d] += P[q][key] * V^T[d][key] ----
#pragma unroll
    for (int kk = 0; kk < 2; ++kk) {
      short8 pa = *(const short8*)(Plb + l15 * 128 + (((kk * 4 + l4) ^ (l15 & 7)) << 4));
#pragma unroll
      for (int nt = 0; nt < 4; ++nt) {
        int d = nt * 16 + l15;
        int slot = (kk * 4 + l4) ^ (l15 & 7);
        short8 vb = *(const short8*)(Vs[cur] + d * 128 + slot * 16);
        o[nt] = __builtin_amdgcn_mfma_f32_16x16x32_bf16(pa, vb, o[nt], 0, 0, 0);
      }
    }

    if (kt == ktmax) break;
    __syncthreads();   // drains vmcnt(0): next tile staged; all waves done w/ cur
  }

  // ---- epilogue: reduce lr, normalize, write ctx ----
  lr += __shfl_xor(lr, 16);
  lr += __shfl_xor(lr, 32);
#pragma unroll
  for (int r = 0; r < 4; ++r) {
    float lrq = __shfl(lr, l4 * 4 + r);
    float inv = __builtin_amdgcn_rcpf(lrq);
    size_t t = (size_t)(b * T_SEQ + q0 + w * 16 + l4 * 4 + r);
#pragma unroll
    for (int nt = 0; nt < 4; ++nt)
      ctx[t * DM + h * HD + nt * 16 + l15] = f2bf(o[nt][r] * inv);
  }
}

// ---------------------------------------------------------------------------
extern "C" void kernel_launch(void* const* d_in, const int* in_sizes, int n_in,
                              void* d_out, int out_size, void* d_ws, size_t ws_size,
                              hipStream_t stream) {
  const float* x = (const float*)d_in[0];
  const float* wqkv = (const float*)d_in[1];
  const float* wout = (const float*)d_in[2];
  float* out = (float*)d_out;
  char* ws = (char*)d_ws;

  u16* xb    = (u16*)(ws);                       //  8 MB
  u16* wqkvb = (u16*)(ws + 8u * 1024 * 1024);    //  6 MB
  u16* woutb = (u16*)(ws + 14u * 1024 * 1024);   //  2 MB
  u16* qkvb  = (u16*)(ws + 16u * 1024 * 1024);   // 24 MB
  u16* ctxb  = (u16*)(ws + 40u * 1024 * 1024);   //  8 MB
  u16* vTb   = (u16*)(ws + 48u * 1024 * 1024);   //  8 MB

  cast_all<<<8192, 256, 0, stream>>>((const float4*)x, (const float4*)wqkv,
                                     (const float4*)wout, (ushort4*)xb);

  gemm_bt<u16><<<dim3(24, 32), 256, 0, stream>>>(xb, wqkvb, qkvb, 4096, 3072, 1024);

  vtrans<<<dim3(8, N_H, N_B), 256, 0, stream>>>(qkvb, vTb);

  attn_fwd<<<dim3(32, N_H, N_B), 256, 0, stream>>>(qkvb, vTb, ctxb);

  gemm_bt<float><<<dim3(8, 32), 256, 0, stream>>>(ctxb, woutb, out, 4096, 1024, 1024);
}